// Round 9
// baseline (123.517 us; speedup 1.0000x reference)
//
#include <hip/hip_runtime.h>
#include <math.h>

// FM layer: logits = bias + segsum(lw[ids]) + 0.5*sum_d((segsum x_d)^2 - segsum(x_d^2))
// outputs: [logits, logits_adjusted, probabilities], each [B], B = out_size/3.
//
// R5 structure (starts table, wave-per-segment, quad gather: 4 lanes/element,
// 16B/lane, quad hits one 128B line) + UNROLL-4 with clamped indices:
// all 4 id loads then all 4 row loads issue back-to-back -> ~64 cache lines
// in flight per wave; a typical 50-element segment completes in ONE load burst
// (one id-wait + one row-wait). Accumulation is exec-mask predicated.

__global__ __launch_bounds__(256) void seg_starts_kernel(
    const int* __restrict__ segs, int* __restrict__ starts, int nnz, int batch)
{
    const int i = blockIdx.x * blockDim.x + threadIdx.x;
    if (i >= nnz) return;
    const int cur = segs[i];
    if (i == 0) {
        for (int b = 0; b <= cur; ++b) starts[b] = 0;
    } else {
        const int prev = segs[i - 1];
        for (int b = prev + 1; b <= cur; ++b) starts[b] = i;
    }
    if (i == nnz - 1) {
        for (int b = cur + 1; b <= batch; ++b) starts[b] = nnz;
    }
}

__global__ __launch_bounds__(256) void fm_fused_kernel(
    const int* __restrict__ ids,
    const int* __restrict__ starts,
    const float* __restrict__ bias,
    const float* __restrict__ lw,
    const float* __restrict__ cw,
    float* __restrict__ out,
    int batch)
{
    const int wave = threadIdx.x >> 6;      // wave in block: 0..3
    const int wl   = threadIdx.x & 63;      // lane in wave
    const int b    = blockIdx.x * 4 + wave; // segment this wave owns
    if (b >= batch) return;

    const int start = starts[b];
    const int end   = starts[b + 1];

    // quad layout: element slot e = wl>>2 (16/iter-step), component c = wl&3.
    const int e = wl >> 2;
    const int c = wl & 3;
    const int coff = c << 2;

    float4 sd = make_float4(0.f, 0.f, 0.f, 0.f);
    float ssq = 0.f, slin = 0.f;

    const int last = end - 1;
    for (int i = start + e; i < end; i += 64) {
        const int i1 = i + 16, i2 = i + 32, i3 = i + 48;
        // clamp (branch-free) so all loads issue unpredicated
        const int j1 = i1 <= last ? i1 : last;
        const int j2 = i2 <= last ? i2 : last;
        const int j3 = i3 <= last ? i3 : last;
        const int id0 = ids[i];
        const int id1 = ids[j1];
        const int id2 = ids[j2];
        const int id3 = ids[j3];
        const float4 x0 = *reinterpret_cast<const float4*>(cw + ((size_t)id0 << 4) + coff);
        const float4 x1 = *reinterpret_cast<const float4*>(cw + ((size_t)id1 << 4) + coff);
        const float4 x2 = *reinterpret_cast<const float4*>(cw + ((size_t)id2 << 4) + coff);
        const float4 x3 = *reinterpret_cast<const float4*>(cw + ((size_t)id3 << 4) + coff);

        if (c == 0) {
            slin += lw[id0];
            if (i1 < end) slin += lw[id1];
            if (i2 < end) slin += lw[id2];
            if (i3 < end) slin += lw[id3];
        }

        sd.x += x0.x; sd.y += x0.y; sd.z += x0.z; sd.w += x0.w;
        ssq = fmaf(x0.x, x0.x, ssq); ssq = fmaf(x0.y, x0.y, ssq);
        ssq = fmaf(x0.z, x0.z, ssq); ssq = fmaf(x0.w, x0.w, ssq);
        if (i1 < end) {
            sd.x += x1.x; sd.y += x1.y; sd.z += x1.z; sd.w += x1.w;
            ssq = fmaf(x1.x, x1.x, ssq); ssq = fmaf(x1.y, x1.y, ssq);
            ssq = fmaf(x1.z, x1.z, ssq); ssq = fmaf(x1.w, x1.w, ssq);
        }
        if (i2 < end) {
            sd.x += x2.x; sd.y += x2.y; sd.z += x2.z; sd.w += x2.w;
            ssq = fmaf(x2.x, x2.x, ssq); ssq = fmaf(x2.y, x2.y, ssq);
            ssq = fmaf(x2.z, x2.z, ssq); ssq = fmaf(x2.w, x2.w, ssq);
        }
        if (i3 < end) {
            sd.x += x3.x; sd.y += x3.y; sd.z += x3.z; sd.w += x3.w;
            ssq = fmaf(x3.x, x3.x, ssq); ssq = fmaf(x3.y, x3.y, ssq);
            ssq = fmaf(x3.z, x3.z, ssq); ssq = fmaf(x3.w, x3.w, ssq);
        }
    }

    // Reduce across the 16 element slots (lanes sharing the same c).
    #pragma unroll
    for (int m = 4; m <= 32; m <<= 1) {
        sd.x += __shfl_xor(sd.x, m);
        sd.y += __shfl_xor(sd.y, m);
        sd.z += __shfl_xor(sd.z, m);
        sd.w += __shfl_xor(sd.w, m);
        ssq  += __shfl_xor(ssq,  m);
        slin += __shfl_xor(slin, m);
    }
    // Each lane now holds complete summed[] for its 4 components.
    float q = sd.x*sd.x + sd.y*sd.y + sd.z*sd.z + sd.w*sd.w;
    #pragma unroll
    for (int m = 1; m <= 2; m <<= 1) {
        q    += __shfl_xor(q,    m);
        ssq  += __shfl_xor(ssq,  m);
        slin += __shfl_xor(slin, m);
    }

    if (wl == 0) {
        const float logit = bias[0] + slin + 0.5f * (q - ssq);
        out[b]             = logit;   // logits
        out[batch + b]     = logit;   // + log(NEG_SAMPLING_RATE=1) == 0
        out[2 * batch + b] = 1.0f / (1.0f + expf(-logit));
    }
}

extern "C" void kernel_launch(void* const* d_in, const int* in_sizes, int n_in,
                              void* d_out, int out_size, void* d_ws, size_t ws_size,
                              hipStream_t stream) {
    const int*   ids  = (const int*)d_in[0];
    const int*   segs = (const int*)d_in[1];
    const float* bias = (const float*)d_in[3];
    const float* lw   = (const float*)d_in[4];
    const float* cw   = (const float*)d_in[5];
    float*       out  = (float*)d_out;

    const int nnz   = in_sizes[0];
    const int batch = out_size / 3;

    int* starts = (int*)d_ws;  // batch+1 ints, fully rewritten every launch

    seg_starts_kernel<<<(nnz + 255) / 256, 256, 0, stream>>>(segs, starts, nnz, batch);

    const int waves_per_block = 4;
    const int grid = (batch + waves_per_block - 1) / waves_per_block;
    fm_fused_kernel<<<grid, 256, 0, stream>>>(ids, starts, bias, lw, cw, out, batch);
}